// Round 3
// baseline (367.985 us; speedup 1.0000x reference)
//
#include <hip/hip_runtime.h>

#define B_   4
#define H_   8
#define M_   2048
#define D_   512
#define DH_  64

typedef short  bf16x8 __attribute__((ext_vector_type(8)));
typedef float  f32x4  __attribute__((ext_vector_type(4)));
typedef unsigned short u16x4 __attribute__((ext_vector_type(4)));

#define EXPC 0.18033688011112042f   /* log2(e)/8 : exp(s/8) == exp2(s*EXPC) */

static __device__ __forceinline__ unsigned short f2bf(float f) {
  unsigned u = __float_as_uint(f);
  u += 0x7fffu + ((u >> 16) & 1u);
  return (unsigned short)(u >> 16);
}

static __device__ __forceinline__ int swz128(int row, int byteoff) {
  return row * 128 + (byteoff ^ ((row & 7) << 4));
}

// ---------------- LayerNorm -> bf16 ----------------
__global__ __launch_bounds__(256) void ln_kernel(
    const float* __restrict__ x, const float* __restrict__ gamma,
    const float* __restrict__ beta, unsigned short* __restrict__ xn)
{
  int row = blockIdx.x;
  int t = threadIdx.x;
  const float* xr = x + (size_t)row * D_;
  float v0 = xr[t], v1 = xr[t + 256];
  float s = v0 + v1, ss = v0 * v0 + v1 * v1;
  #pragma unroll
  for (int m = 1; m < 64; m <<= 1) {
    s  += __shfl_xor(s, m);
    ss += __shfl_xor(ss, m);
  }
  __shared__ float red[8];
  int wid = t >> 6;
  if ((t & 63) == 0) { red[wid] = s; red[wid + 4] = ss; }
  __syncthreads();
  s  = red[0] + red[1] + red[2] + red[3];
  ss = red[4] + red[5] + red[6] + red[7];
  float mu  = s * (1.0f / D_);
  float var = ss * (1.0f / D_) - mu * mu;
  float rstd = rsqrtf(var + 1e-5f);
  unsigned short* o = xn + (size_t)row * D_;
  o[t]       = f2bf((v0 - mu) * rstd * gamma[t]       + beta[t]);
  o[t + 256] = f2bf((v1 - mu) * rstd * gamma[t + 256] + beta[t + 256]);
}

// ---------------- weight casts ----------------
__global__ __launch_bounds__(256) void cast_w_kernel(
    const float* __restrict__ wq, const float* __restrict__ wk,
    const float* __restrict__ wv, const float* __restrict__ wo,
    unsigned short* __restrict__ wqkv, unsigned short* __restrict__ wob)
{
  int i = blockIdx.x * 256 + threadIdx.x;   // 262144 total
  wqkv[i]          = f2bf(wq[i]);
  wqkv[i + 262144] = f2bf(wk[i]);
  wqkv[i + 524288] = f2bf(wv[i]);
  wob[i]           = f2bf(wo[i]);
}

// ---------------- QKV GEMM: [8192,512] x [1536,512]^T ----------------
// blockIdx.y 0-3: q (swapped epilogue), 4-7: k (swapped), 8-11: v (unswapped)
__global__ __launch_bounds__(256) void qkv_gemm(
    const unsigned short* __restrict__ xn,
    const unsigned short* __restrict__ wqkv,
    const float* __restrict__ bq, const float* __restrict__ bk,
    const float* __restrict__ bv,
    unsigned short* __restrict__ q, unsigned short* __restrict__ k,
    unsigned short* __restrict__ vT)
{
  __shared__ __align__(16) char As[128 * 128];
  __shared__ __align__(16) char Bs[128 * 128];
  const int m0 = blockIdx.x * 128;
  const int n0 = blockIdx.y * 128;
  const int t = threadIdx.x, wid = t >> 6, lane = t & 63;
  const int wr = (wid >> 1) * 64, wc = (wid & 1) * 64;
  const int cl = lane & 15, rg = lane >> 4;
  const f32x4 z4 = {0.f, 0.f, 0.f, 0.f};
  const bool isv = (n0 >= 1024);

  f32x4 acc[4][4];
  #pragma unroll
  for (int i = 0; i < 4; ++i)
    #pragma unroll
    for (int j = 0; j < 4; ++j) acc[i][j] = z4;

  for (int k0 = 0; k0 < 512; k0 += 64) {
    __syncthreads();
    #pragma unroll
    for (int i = 0; i < 4; ++i) {
      int c = t + 256 * i;
      int row = c >> 3, off = (c & 7) * 16;
      *(uint4*)(As + swz128(row, off)) =
          *(const uint4*)((const char*)(xn + (size_t)(m0 + row) * 512 + k0) + off);
      *(uint4*)(Bs + swz128(row, off)) =
          *(const uint4*)((const char*)(wqkv + (size_t)(n0 + row) * 512 + k0) + off);
    }
    __syncthreads();
    #pragma unroll
    for (int ks = 0; ks < 2; ++ks) {
      int koff = ks * 64 + rg * 16;
      bf16x8 af[4], bfr[4];
      #pragma unroll
      for (int i = 0; i < 4; ++i)
        af[i] = *(const bf16x8*)(As + swz128(wr + i * 16 + cl, koff));
      #pragma unroll
      for (int j = 0; j < 4; ++j)
        bfr[j] = *(const bf16x8*)(Bs + swz128(wc + j * 16 + cl, koff));
      if (isv) {
        #pragma unroll
        for (int i = 0; i < 4; ++i)
          #pragma unroll
          for (int j = 0; j < 4; ++j)
            acc[i][j] = __builtin_amdgcn_mfma_f32_16x16x32_bf16(af[i], bfr[j], acc[i][j], 0, 0, 0);
      } else {
        #pragma unroll
        for (int j = 0; j < 4; ++j)
          #pragma unroll
          for (int i = 0; i < 4; ++i)
            acc[j][i] = __builtin_amdgcn_mfma_f32_16x16x32_bf16(bfr[j], af[i], acc[j][i], 0, 0, 0);
      }
    }
  }

  if (isv) {
    // acc[i][j]: C[m = wr+i*16+rg*4+r][n = wc+j*16+cl]; 4 consecutive m -> vT cols
    #pragma unroll
    for (int j = 0; j < 4; ++j) {
      int n = n0 + wc + j * 16 + cl;          // 1024..1535
      int nn = n & 511;
      int h = nn >> 6, dh = nn & 63;
      float bias = bv[nn];
      #pragma unroll
      for (int i = 0; i < 4; ++i) {
        int mrow = m0 + wr + i * 16 + rg * 4;
        int b = mrow >> 11, mm = mrow & 2047;
        u16x4 u;
        #pragma unroll
        for (int r = 0; r < 4; ++r) u[r] = f2bf(acc[i][j][r] + bias);
        *(u16x4*)(vT + ((size_t)(b * H_ + h) * DH_ + dh) * M_ + mm) = u;
      }
    }
  } else {
    // acc[j][i]: C[n = n0+wc+j*16+rg*4+r][m = m0+wr+i*16+cl]; 4 consecutive n -> q/k dh
    const int mat = n0 >> 9;                  // 0: q, 1: k
    unsigned short* dst = mat ? k : q;
    const float* bias = mat ? bk : bq;
    #pragma unroll
    for (int j = 0; j < 4; ++j) {
      int nn0 = ((n0 + wc) & 511) + j * 16 + rg * 4;
      int h = nn0 >> 6, dh = nn0 & 63;
      f32x4 b4 = *(const f32x4*)(bias + nn0);
      #pragma unroll
      for (int i = 0; i < 4; ++i) {
        int mrow = m0 + wr + i * 16 + cl;
        int b = mrow >> 11, mm = mrow & 2047;
        u16x4 u;
        #pragma unroll
        for (int r = 0; r < 4; ++r) u[r] = f2bf(acc[j][i][r] + b4[r]);
        *(u16x4*)(dst + ((size_t)(b * H_ + h) * M_ + mm) * DH_ + dh) = u;
      }
    }
  }
}

// ---------------- Attention v3: barrier-free, direct-global fragments ----------------
// grid: (32 m-blocks of 64 rows, 32 bh). block = 256 (4 waves x 16 Q-rows each).
__global__ __launch_bounds__(256) void attn_kernel(
    const unsigned short* __restrict__ q,
    const unsigned short* __restrict__ k,
    const unsigned short* __restrict__ vT,
    float* __restrict__ attn,
    unsigned short* __restrict__ ctx)
{
  __shared__ __align__(16) char Ps[4 * 2048];   // per-wave 16 rows x 128 B

  const int bh = blockIdx.y;
  const int m0 = blockIdx.x * 64;
  const int t = threadIdx.x, wid = t >> 6, lane = t & 63;
  const int wr = wid * 16;
  const int cl = lane & 15, rg = lane >> 4;
  const f32x4 z4 = {0.f, 0.f, 0.f, 0.f};
  const int diag_kt = m0 >> 6;
  const int m_g = m0 + wr + cl;
  char* Pw = Ps + wid * 2048;

  const char* qb = (const char*)(q  + (size_t)bh * M_ * DH_);
  const char* kb = (const char*)(k  + (size_t)bh * M_ * DH_);
  const char* vb = (const char*)(vT + (size_t)bh * DH_ * M_);
  float* ab = attn + (size_t)bh * M_ * M_;

  // Q fragments straight from global (B-operand: col = m)
  bf16x8 qf[2];
  #pragma unroll
  for (int ks = 0; ks < 2; ++ks)
    qf[ks] = *(const bf16x8*)(qb + (size_t)m_g * 128 + ks * 64 + rg * 16);

  // ---- pass 1: row sums of exp2(s*EXPC) ----
  float psum = 0.f;
  for (int kt = 0; kt < 32; ++kt) {
    const char* kbase = kb + (size_t)kt * 64 * 128;
    f32x4 s[4];
    #pragma unroll
    for (int j = 0; j < 4; ++j) s[j] = z4;
    #pragma unroll
    for (int ks = 0; ks < 2; ++ks) {
      #pragma unroll
      for (int j = 0; j < 4; ++j) {
        bf16x8 kf = *(const bf16x8*)(kbase + (size_t)(j * 16 + cl) * 128 + ks * 64 + rg * 16);
        s[j] = __builtin_amdgcn_mfma_f32_16x16x32_bf16(kf, qf[ks], s[j], 0, 0, 0);
      }
    }
    if (kt == diag_kt) {
      #pragma unroll
      for (int j = 0; j < 4; ++j)
        #pragma unroll
        for (int r = 0; r < 4; ++r) {
          int n_g = kt * 64 + j * 16 + rg * 4 + r;
          float p = __builtin_amdgcn_exp2f(s[j][r] * EXPC);
          psum += (n_g == m_g) ? 0.f : p;
        }
    } else {
      #pragma unroll
      for (int j = 0; j < 4; ++j)
        #pragma unroll
        for (int r = 0; r < 4; ++r)
          psum += __builtin_amdgcn_exp2f(s[j][r] * EXPC);
    }
  }
  psum += __shfl_xor(psum, 16);
  psum += __shfl_xor(psum, 32);
  const float rinv = 1.0f / psum;

  // ---- pass 2: recompute S, write normalized attn (float4 NT), PV ----
  f32x4 oc[4];
  #pragma unroll
  for (int j = 0; j < 4; ++j) oc[j] = z4;

  for (int kt = 0; kt < 32; ++kt) {
    const char* kbase = kb + (size_t)kt * 64 * 128;
    f32x4 s[4];
    #pragma unroll
    for (int j = 0; j < 4; ++j) s[j] = z4;
    #pragma unroll
    for (int ks = 0; ks < 2; ++ks) {
      #pragma unroll
      for (int j = 0; j < 4; ++j) {
        bf16x8 kf = *(const bf16x8*)(kbase + (size_t)(j * 16 + cl) * 128 + ks * 64 + rg * 16);
        s[j] = __builtin_amdgcn_mfma_f32_16x16x32_bf16(kf, qf[ks], s[j], 0, 0, 0);
      }
    }
    // emit P: lane holds 4 consecutive n for its row m_g
    const bool dtile = (kt == diag_kt);
    float* arow = ab + (size_t)m_g * M_ + kt * 64 + rg * 4;
    #pragma unroll
    for (int j = 0; j < 4; ++j) {
      f32x4 pv;
      #pragma unroll
      for (int r = 0; r < 4; ++r) {
        int n_g = kt * 64 + j * 16 + rg * 4 + r;
        float p = __builtin_amdgcn_exp2f(s[j][r] * EXPC) * rinv;
        pv[r] = (dtile && n_g == m_g) ? 0.f : p;
      }
      __builtin_nontemporal_store(pv, (f32x4*)(arow + j * 16));
      u16x4 u;
      #pragma unroll
      for (int r = 0; r < 4; ++r) u[r] = f2bf(pv[r]);
      *(u16x4*)(Pw + swz128(cl, j * 32 + rg * 8)) = u;      // per-wave region: no barrier
    }
    // PV: oc[jd] += V_frag x P_frag   (V fragments straight from global vT)
    #pragma unroll
    for (int ks = 0; ks < 2; ++ks) {
      bf16x8 pf = *(const bf16x8*)(Pw + swz128(cl, ks * 64 + rg * 16));
      #pragma unroll
      for (int jd = 0; jd < 4; ++jd) {
        bf16x8 vf = *(const bf16x8*)(vb + (size_t)(jd * 16 + cl) * (M_ * 2) + kt * 128 + rg * 16);
        oc[jd] = __builtin_amdgcn_mfma_f32_16x16x32_bf16(vf, pf, oc[jd], 0, 0, 0);
      }
    }
  }

  // ctx epilogue: lane holds 4 consecutive d for its row m_g -> 8B stores
  int b = bh >> 3, h = bh & 7;
  unsigned short* crow = ctx + ((size_t)b * M_ + m_g) * D_ + h * DH_ + rg * 4;
  #pragma unroll
  for (int jd = 0; jd < 4; ++jd) {
    u16x4 u;
    #pragma unroll
    for (int r = 0; r < 4; ++r) u[r] = f2bf(oc[jd][r]);
    *(u16x4*)(crow + jd * 16) = u;
  }
}

// ---------------- out = ctx @ wo^T + bo + x (swapped epilogue, float4) ----------------
__global__ __launch_bounds__(256) void out_gemm(
    const unsigned short* __restrict__ ctxb,
    const unsigned short* __restrict__ wob,
    const float* __restrict__ bo,
    const float* __restrict__ x,
    float* __restrict__ out)
{
  __shared__ __align__(16) char As[128 * 128];
  __shared__ __align__(16) char Bs[128 * 128];
  const int m0 = blockIdx.x * 128;
  const int n0 = blockIdx.y * 128;
  const int t = threadIdx.x, wid = t >> 6, lane = t & 63;
  const int wr = (wid >> 1) * 64, wc = (wid & 1) * 64;
  const int cl = lane & 15, rg = lane >> 4;
  const f32x4 z4 = {0.f, 0.f, 0.f, 0.f};

  f32x4 acc[4][4];   // [j: n frag][i: m frag], row=n, col=m
  #pragma unroll
  for (int j = 0; j < 4; ++j)
    #pragma unroll
    for (int i = 0; i < 4; ++i) acc[j][i] = z4;

  for (int k0 = 0; k0 < 512; k0 += 64) {
    __syncthreads();
    #pragma unroll
    for (int i = 0; i < 4; ++i) {
      int c = t + 256 * i;
      int row = c >> 3, off = (c & 7) * 16;
      *(uint4*)(As + swz128(row, off)) =
          *(const uint4*)((const char*)(ctxb + (size_t)(m0 + row) * 512 + k0) + off);
      *(uint4*)(Bs + swz128(row, off)) =
          *(const uint4*)((const char*)(wob + (size_t)(n0 + row) * 512 + k0) + off);
    }
    __syncthreads();
    #pragma unroll
    for (int ks = 0; ks < 2; ++ks) {
      int koff = ks * 64 + rg * 16;
      bf16x8 af[4], bfr[4];
      #pragma unroll
      for (int i = 0; i < 4; ++i)
        af[i] = *(const bf16x8*)(As + swz128(wr + i * 16 + cl, koff));
      #pragma unroll
      for (int j = 0; j < 4; ++j)
        bfr[j] = *(const bf16x8*)(Bs + swz128(wc + j * 16 + cl, koff));
      #pragma unroll
      for (int j = 0; j < 4; ++j)
        #pragma unroll
        for (int i = 0; i < 4; ++i)
          acc[j][i] = __builtin_amdgcn_mfma_f32_16x16x32_bf16(bfr[j], af[i], acc[j][i], 0, 0, 0);
    }
  }

  #pragma unroll
  for (int j = 0; j < 4; ++j) {
    int nb = n0 + wc + j * 16 + rg * 4;
    f32x4 bo4 = *(const f32x4*)(bo + nb);
    #pragma unroll
    for (int i = 0; i < 4; ++i) {
      int m = m0 + wr + i * 16 + cl;
      f32x4 x4 = *(const f32x4*)(x + (size_t)m * 512 + nb);
      f32x4 o;
      #pragma unroll
      for (int r = 0; r < 4; ++r) o[r] = acc[j][i][r] + bo4[r] + x4[r];
      *(f32x4*)(out + (size_t)m * 512 + nb) = o;
    }
  }
}

extern "C" void kernel_launch(void* const* d_in, const int* in_sizes, int n_in,
                              void* d_out, int out_size, void* d_ws, size_t ws_size,
                              hipStream_t stream) {
  const float* x     = (const float*)d_in[0];
  const float* wq    = (const float*)d_in[1];
  const float* bq    = (const float*)d_in[2];
  const float* wk    = (const float*)d_in[3];
  const float* bk    = (const float*)d_in[4];
  const float* wv    = (const float*)d_in[5];
  const float* bv    = (const float*)d_in[6];
  const float* wo    = (const float*)d_in[7];
  const float* bo    = (const float*)d_in[8];
  const float* gamma = (const float*)d_in[9];
  const float* beta  = (const float*)d_in[10];

  char* ws = (char*)d_ws;
  unsigned short* xn   = (unsigned short*)(ws);              //  8,388,608 B
  unsigned short* wqkv = (unsigned short*)(ws + 8388608);    //  1,572,864 B
  unsigned short* wob  = (unsigned short*)(ws + 9961472);    //    524,288 B
  unsigned short* qb   = (unsigned short*)(ws + 10485760);   //  8,388,608 B
  unsigned short* kb   = (unsigned short*)(ws + 18874368);   //  8,388,608 B
  unsigned short* vT   = (unsigned short*)(ws + 27262976);   //  8,388,608 B
  unsigned short* ctx  = (unsigned short*)(ws + 35651584);   //  8,388,608 B

  float* out  = (float*)d_out;
  float* attn = (float*)d_out + 4194304;

  ln_kernel<<<8192, 256, 0, stream>>>(x, gamma, beta, xn);
  cast_w_kernel<<<1024, 256, 0, stream>>>(wq, wk, wv, wo, wqkv, wob);
  qkv_gemm<<<dim3(64, 12), 256, 0, stream>>>(xn, wqkv, bq, bk, bv, qb, kb, vT);
  attn_kernel<<<dim3(32, 32), 256, 0, stream>>>(qb, kb, vT, attn, ctx);
  out_gemm<<<dim3(64, 4), 256, 0, stream>>>(ctx, wob, bo, x, out);
}

// Round 4
// 215.756 us; speedup vs baseline: 1.7056x; 1.7056x over previous
//
#include <hip/hip_runtime.h>

#define B_   4
#define H_   8
#define M_   2048
#define D_   512
#define DH_  64

typedef short  bf16x8 __attribute__((ext_vector_type(8)));
typedef float  f32x4  __attribute__((ext_vector_type(4)));
typedef unsigned short u16x4 __attribute__((ext_vector_type(4)));

#define EXPC 0.18033688011112042f   /* log2(e)/8 : exp(s/8) == exp2(s*EXPC) */

static __device__ __forceinline__ unsigned short f2bf(float f) {
  unsigned u = __float_as_uint(f);
  u += 0x7fffu + ((u >> 16) & 1u);
  return (unsigned short)(u >> 16);
}

static __device__ __forceinline__ int swz128(int row, int byteoff) {
  return row * 128 + (byteoff ^ ((row & 7) << 4));
}

// async global->LDS, 16B per lane, LDS dest = wave-uniform base + lane*16
static __device__ __forceinline__ void glds16(const void* g, void* l) {
  __builtin_amdgcn_global_load_lds(
      (const __attribute__((address_space(1))) unsigned*)g,
      (__attribute__((address_space(3))) unsigned*)l, 16, 0, 0);
}

// ---------------- LayerNorm -> bf16 ----------------
__global__ __launch_bounds__(256) void ln_kernel(
    const float* __restrict__ x, const float* __restrict__ gamma,
    const float* __restrict__ beta, unsigned short* __restrict__ xn)
{
  int row = blockIdx.x;
  int t = threadIdx.x;
  const float* xr = x + (size_t)row * D_;
  float v0 = xr[t], v1 = xr[t + 256];
  float s = v0 + v1, ss = v0 * v0 + v1 * v1;
  #pragma unroll
  for (int m = 1; m < 64; m <<= 1) {
    s  += __shfl_xor(s, m);
    ss += __shfl_xor(ss, m);
  }
  __shared__ float red[8];
  int wid = t >> 6;
  if ((t & 63) == 0) { red[wid] = s; red[wid + 4] = ss; }
  __syncthreads();
  s  = red[0] + red[1] + red[2] + red[3];
  ss = red[4] + red[5] + red[6] + red[7];
  float mu  = s * (1.0f / D_);
  float var = ss * (1.0f / D_) - mu * mu;
  float rstd = rsqrtf(var + 1e-5f);
  unsigned short* o = xn + (size_t)row * D_;
  o[t]       = f2bf((v0 - mu) * rstd * gamma[t]       + beta[t]);
  o[t + 256] = f2bf((v1 - mu) * rstd * gamma[t + 256] + beta[t + 256]);
}

// ---------------- weight casts ----------------
__global__ __launch_bounds__(256) void cast_w_kernel(
    const float* __restrict__ wq, const float* __restrict__ wk,
    const float* __restrict__ wv, const float* __restrict__ wo,
    unsigned short* __restrict__ wqkv, unsigned short* __restrict__ wob)
{
  int i = blockIdx.x * 256 + threadIdx.x;   // 262144 total
  wqkv[i]          = f2bf(wq[i]);
  wqkv[i + 262144] = f2bf(wk[i]);
  wqkv[i + 524288] = f2bf(wv[i]);
  wob[i]           = f2bf(wo[i]);
}

// ---------------- QKV GEMM: [8192,512] x [1536,512]^T ----------------
__global__ __launch_bounds__(256) void qkv_gemm(
    const unsigned short* __restrict__ xn,
    const unsigned short* __restrict__ wqkv,
    const float* __restrict__ bq, const float* __restrict__ bk,
    const float* __restrict__ bv,
    unsigned short* __restrict__ q, unsigned short* __restrict__ k,
    unsigned short* __restrict__ vT)
{
  __shared__ __align__(16) char As[128 * 128];
  __shared__ __align__(16) char Bs[128 * 128];
  const int m0 = blockIdx.x * 128;
  const int n0 = blockIdx.y * 128;
  const int t = threadIdx.x, wid = t >> 6, lane = t & 63;
  const int wr = (wid >> 1) * 64, wc = (wid & 1) * 64;
  const int cl = lane & 15, rg = lane >> 4;
  const f32x4 z4 = {0.f, 0.f, 0.f, 0.f};
  const bool isv = (n0 >= 1024);

  f32x4 acc[4][4];
  #pragma unroll
  for (int i = 0; i < 4; ++i)
    #pragma unroll
    for (int j = 0; j < 4; ++j) acc[i][j] = z4;

  for (int k0 = 0; k0 < 512; k0 += 64) {
    __syncthreads();
    #pragma unroll
    for (int i = 0; i < 4; ++i) {
      int c = t + 256 * i;
      int row = c >> 3, off = (c & 7) * 16;
      *(uint4*)(As + swz128(row, off)) =
          *(const uint4*)((const char*)(xn + (size_t)(m0 + row) * 512 + k0) + off);
      *(uint4*)(Bs + swz128(row, off)) =
          *(const uint4*)((const char*)(wqkv + (size_t)(n0 + row) * 512 + k0) + off);
    }
    __syncthreads();
    #pragma unroll
    for (int ks = 0; ks < 2; ++ks) {
      int koff = ks * 64 + rg * 16;
      bf16x8 af[4], bfr[4];
      #pragma unroll
      for (int i = 0; i < 4; ++i)
        af[i] = *(const bf16x8*)(As + swz128(wr + i * 16 + cl, koff));
      #pragma unroll
      for (int j = 0; j < 4; ++j)
        bfr[j] = *(const bf16x8*)(Bs + swz128(wc + j * 16 + cl, koff));
      if (isv) {
        #pragma unroll
        for (int i = 0; i < 4; ++i)
          #pragma unroll
          for (int j = 0; j < 4; ++j)
            acc[i][j] = __builtin_amdgcn_mfma_f32_16x16x32_bf16(af[i], bfr[j], acc[i][j], 0, 0, 0);
      } else {
        #pragma unroll
        for (int j = 0; j < 4; ++j)
          #pragma unroll
          for (int i = 0; i < 4; ++i)
            acc[j][i] = __builtin_amdgcn_mfma_f32_16x16x32_bf16(bfr[j], af[i], acc[j][i], 0, 0, 0);
      }
    }
  }

  if (isv) {
    #pragma unroll
    for (int j = 0; j < 4; ++j) {
      int n = n0 + wc + j * 16 + cl;
      int nn = n & 511;
      int h = nn >> 6, dh = nn & 63;
      float bias = bv[nn];
      #pragma unroll
      for (int i = 0; i < 4; ++i) {
        int mrow = m0 + wr + i * 16 + rg * 4;
        int b = mrow >> 11, mm = mrow & 2047;
        u16x4 u;
        #pragma unroll
        for (int r = 0; r < 4; ++r) u[r] = f2bf(acc[i][j][r] + bias);
        *(u16x4*)(vT + ((size_t)(b * H_ + h) * DH_ + dh) * M_ + mm) = u;
      }
    }
  } else {
    const int mat = n0 >> 9;                  // 0: q, 1: k
    unsigned short* dst = mat ? k : q;
    const float* bias = mat ? bk : bq;
    #pragma unroll
    for (int j = 0; j < 4; ++j) {
      int nn0 = ((n0 + wc) & 511) + j * 16 + rg * 4;
      int h = nn0 >> 6, dh = nn0 & 63;
      f32x4 b4 = *(const f32x4*)(bias + nn0);
      #pragma unroll
      for (int i = 0; i < 4; ++i) {
        int mrow = m0 + wr + i * 16 + cl;
        int b = mrow >> 11, mm = mrow & 2047;
        u16x4 u;
        #pragma unroll
        for (int r = 0; r < 4; ++r) u[r] = f2bf(acc[j][i][r] + b4[r]);
        *(u16x4*)(dst + ((size_t)(b * H_ + h) * M_ + mm) * DH_ + dh) = u;
      }
    }
  }
}

// ---------------- psum: rinv[bh][m] = 1/sum_n exp(s/8), diag excluded -------
// grid 1024 (XCD-swizzled -> (bh, mb)); 64 rows/block, K dbuf via glds.
__global__ __launch_bounds__(256, 8) void psum_kernel(
    const unsigned short* __restrict__ q, const unsigned short* __restrict__ k,
    float* __restrict__ rinv)
{
  __shared__ __align__(16) char Kb[2][8192];
  const int flat = blockIdx.x;
  const int bh = (flat & 7) * 4 + ((flat >> 3) >> 5);
  const int mb = (flat >> 3) & 31;
  const int m0 = mb * 64;
  const int t = threadIdx.x, wid = t >> 6, lane = t & 63;
  const int wr = wid * 16, cl = lane & 15, rg = lane >> 4;
  const char* qb = (const char*)(q + (size_t)bh * M_ * DH_);
  const char* kb = (const char*)(k + (size_t)bh * M_ * DH_);
  const int m_g = m0 + wr + cl;
  const f32x4 z4 = {0.f, 0.f, 0.f, 0.f};

  bf16x8 qf[2];
  #pragma unroll
  for (int ks = 0; ks < 2; ++ks)
    qf[ks] = *(const bf16x8*)(qb + (size_t)m_g * 128 + ks * 64 + rg * 16);

  // staging geometry: lane-linear LDS, inverse-swizzled global source
  const int r0 = t >> 3, c0 = t & 7;
  const int ldsoff = (t & 192) * 16;                       // wave-uniform
  const size_t sK0 = (size_t)r0 * 128 + ((c0 ^ (r0 & 7)) << 4);

  glds16(kb + sK0,        Kb[0] + ldsoff);
  glds16(kb + sK0 + 4096, Kb[0] + ldsoff + 4096);

  float psum = 0.f;
  int buf = 0;
  for (int nt = 0; nt < 32; ++nt) {
    __syncthreads();
    if (nt + 1 < 32) {
      const char* src = kb + (size_t)(nt + 1) * 8192;
      glds16(src + sK0,        Kb[buf ^ 1] + ldsoff);
      glds16(src + sK0 + 4096, Kb[buf ^ 1] + ldsoff + 4096);
    }
    f32x4 s[4];
    #pragma unroll
    for (int j = 0; j < 4; ++j) s[j] = z4;
    #pragma unroll
    for (int ks = 0; ks < 2; ++ks)
      #pragma unroll
      for (int j = 0; j < 4; ++j) {
        bf16x8 kf = *(const bf16x8*)(Kb[buf] + swz128(j * 16 + cl, ks * 64 + rg * 16));
        s[j] = __builtin_amdgcn_mfma_f32_16x16x32_bf16(kf, qf[ks], s[j], 0, 0, 0);
      }
    if (nt == mb) {
      #pragma unroll
      for (int j = 0; j < 4; ++j)
        #pragma unroll
        for (int r = 0; r < 4; ++r) {
          int n_g = nt * 64 + j * 16 + rg * 4 + r;
          float p = __builtin_amdgcn_exp2f(s[j][r] * EXPC);
          psum += (n_g == m_g) ? 0.f : p;
        }
    } else {
      #pragma unroll
      for (int j = 0; j < 4; ++j)
        #pragma unroll
        for (int r = 0; r < 4; ++r)
          psum += __builtin_amdgcn_exp2f(s[j][r] * EXPC);
    }
    buf ^= 1;
  }
  psum += __shfl_xor(psum, 16);
  psum += __shfl_xor(psum, 32);
  if (lane < 16) rinv[bh * M_ + m_g] = 1.0f / psum;
}

// ---------------- Attention v4: single pass, dbuf glds staging --------------
// grid 1024 (XCD-swizzled); 64 rows/block, 4 waves x 16 rows.
__global__ __launch_bounds__(256, 4) void attn_kernel(
    const unsigned short* __restrict__ q,
    const unsigned short* __restrict__ k,
    const unsigned short* __restrict__ vT,
    const float* __restrict__ rinv,
    float* __restrict__ attn,
    unsigned short* __restrict__ ctx)
{
  __shared__ __align__(16) char Kb[2][8192];
  __shared__ __align__(16) char Vb[2][8192];
  __shared__ __align__(16) char Ps[4][2048];

  const int flat = blockIdx.x;
  const int bh = (flat & 7) * 4 + ((flat >> 3) >> 5);
  const int mb = (flat >> 3) & 31;
  const int m0 = mb * 64;
  const int t = threadIdx.x, wid = t >> 6, lane = t & 63;
  const int wr = wid * 16, cl = lane & 15, rg = lane >> 4;
  const int m_g = m0 + wr + cl;
  const f32x4 z4 = {0.f, 0.f, 0.f, 0.f};

  const char* qb = (const char*)(q  + (size_t)bh * M_ * DH_);
  const char* kb = (const char*)(k  + (size_t)bh * M_ * DH_);
  const char* vb = (const char*)(vT + (size_t)bh * DH_ * M_);
  float* ab = attn + (size_t)bh * M_ * M_;

  const float rv = rinv[bh * M_ + m_g];
  bf16x8 qf[2];
  #pragma unroll
  for (int ks = 0; ks < 2; ++ks)
    qf[ks] = *(const bf16x8*)(qb + (size_t)m_g * 128 + ks * 64 + rg * 16);

  // staging geometry
  const int r0 = t >> 3, c0 = t & 7;
  const int ldsoff = (t & 192) * 16;                       // wave-uniform
  const size_t sK0 = (size_t)r0 * 128 + ((c0 ^ (r0 & 7)) << 4);
  const size_t sV0 = (size_t)r0 * (M_ * 2) + ((c0 ^ (r0 & 7)) << 4);

  glds16(kb + sK0,                    Kb[0] + ldsoff);
  glds16(kb + sK0 + 4096,             Kb[0] + ldsoff + 4096);
  glds16(vb + sV0,                    Vb[0] + ldsoff);
  glds16(vb + sV0 + 32 * (M_ * 2),    Vb[0] + ldsoff + 4096);

  f32x4 oc[4];
  #pragma unroll
  for (int j = 0; j < 4; ++j) oc[j] = z4;

  const int srow = lane >> 4;          // attn-store row-in-group 0..3
  const int sch  = lane & 15;          // attn-store 8B-chunk 0..15

  int buf = 0;
  for (int nt = 0; nt < 32; ++nt) {
    __syncthreads();
    if (nt + 1 < 32) {
      const char* srcK = kb + (size_t)(nt + 1) * 8192;
      const char* srcV = vb + (size_t)(nt + 1) * 128;
      glds16(srcK + sK0,                 Kb[buf ^ 1] + ldsoff);
      glds16(srcK + sK0 + 4096,          Kb[buf ^ 1] + ldsoff + 4096);
      glds16(srcV + sV0,                 Vb[buf ^ 1] + ldsoff);
      glds16(srcV + sV0 + 32 * (M_ * 2), Vb[buf ^ 1] + ldsoff + 4096);
    }
    // QK^T (swapped: rows = n, cols = m)
    f32x4 s[4];
    #pragma unroll
    for (int j = 0; j < 4; ++j) s[j] = z4;
    #pragma unroll
    for (int ks = 0; ks < 2; ++ks)
      #pragma unroll
      for (int j = 0; j < 4; ++j) {
        bf16x8 kf = *(const bf16x8*)(Kb[buf] + swz128(j * 16 + cl, ks * 64 + rg * 16));
        s[j] = __builtin_amdgcn_mfma_f32_16x16x32_bf16(kf, qf[ks], s[j], 0, 0, 0);
      }
    // normalized P -> per-wave LDS (bf16)
    const bool dtile = (nt == mb);
    #pragma unroll
    for (int j = 0; j < 4; ++j) {
      u16x4 u;
      #pragma unroll
      for (int r = 0; r < 4; ++r) {
        int n_g = nt * 64 + j * 16 + rg * 4 + r;
        float p = __builtin_amdgcn_exp2f(s[j][r] * EXPC) * rv;
        u[r] = f2bf((dtile && n_g == m_g) ? 0.f : p);
      }
      *(u16x4*)(Ps[wid] + swz128(cl, j * 32 + rg * 8)) = u;
    }
    // attn store: full-width rows (4 rows x 256B per instruction)
    {
      float* abase = ab + ((size_t)(m0 + wr + srow)) * M_ + nt * 64 + sch * 4;
      #pragma unroll
      for (int it = 0; it < 4; ++it) {
        u16x4 pu = *(const u16x4*)(Ps[wid] + swz128(it * 4 + srow, sch * 8));
        f32x4 pv;
        #pragma unroll
        for (int r = 0; r < 4; ++r) pv[r] = __uint_as_float((unsigned)pu[r] << 16);
        __builtin_nontemporal_store(pv, (f32x4*)(abase + (size_t)it * 4 * M_));
      }
    }
    // PV (swapped: rows = d, cols = m)
    #pragma unroll
    for (int ks = 0; ks < 2; ++ks) {
      bf16x8 pf = *(const bf16x8*)(Ps[wid] + swz128(cl, ks * 64 + rg * 16));
      #pragma unroll
      for (int jd = 0; jd < 4; ++jd) {
        bf16x8 vf = *(const bf16x8*)(Vb[buf] + swz128(jd * 16 + cl, ks * 64 + rg * 16));
        oc[jd] = __builtin_amdgcn_mfma_f32_16x16x32_bf16(vf, pf, oc[jd], 0, 0, 0);
      }
    }
    buf ^= 1;
  }

  // ctx epilogue: lane holds 4 consecutive d for its row m_g
  int b = bh >> 3, h = bh & 7;
  unsigned short* crow = ctx + ((size_t)b * M_ + m_g) * D_ + h * DH_ + rg * 4;
  #pragma unroll
  for (int jd = 0; jd < 4; ++jd) {
    u16x4 u;
    #pragma unroll
    for (int r = 0; r < 4; ++r) u[r] = f2bf(oc[jd][r]);
    *(u16x4*)(crow + jd * 16) = u;
  }
}

// ---------------- out = ctx @ wo^T + bo + x (swapped epilogue, float4) ------
__global__ __launch_bounds__(256) void out_gemm(
    const unsigned short* __restrict__ ctxb,
    const unsigned short* __restrict__ wob,
    const float* __restrict__ bo,
    const float* __restrict__ x,
    float* __restrict__ out)
{
  __shared__ __align__(16) char As[128 * 128];
  __shared__ __align__(16) char Bs[128 * 128];
  const int m0 = blockIdx.x * 128;
  const int n0 = blockIdx.y * 128;
  const int t = threadIdx.x, wid = t >> 6, lane = t & 63;
  const int wr = (wid >> 1) * 64, wc = (wid & 1) * 64;
  const int cl = lane & 15, rg = lane >> 4;
  const f32x4 z4 = {0.f, 0.f, 0.f, 0.f};

  f32x4 acc[4][4];   // [j: n frag][i: m frag], row=n, col=m
  #pragma unroll
  for (int j = 0; j < 4; ++j)
    #pragma unroll
    for (int i = 0; i < 4; ++i) acc[j][i] = z4;

  for (int k0 = 0; k0 < 512; k0 += 64) {
    __syncthreads();
    #pragma unroll
    for (int i = 0; i < 4; ++i) {
      int c = t + 256 * i;
      int row = c >> 3, off = (c & 7) * 16;
      *(uint4*)(As + swz128(row, off)) =
          *(const uint4*)((const char*)(ctxb + (size_t)(m0 + row) * 512 + k0) + off);
      *(uint4*)(Bs + swz128(row, off)) =
          *(const uint4*)((const char*)(wob + (size_t)(n0 + row) * 512 + k0) + off);
    }
    __syncthreads();
    #pragma unroll
    for (int ks = 0; ks < 2; ++ks) {
      int koff = ks * 64 + rg * 16;
      bf16x8 af[4], bfr[4];
      #pragma unroll
      for (int i = 0; i < 4; ++i)
        af[i] = *(const bf16x8*)(As + swz128(wr + i * 16 + cl, koff));
      #pragma unroll
      for (int j = 0; j < 4; ++j)
        bfr[j] = *(const bf16x8*)(Bs + swz128(wc + j * 16 + cl, koff));
      #pragma unroll
      for (int j = 0; j < 4; ++j)
        #pragma unroll
        for (int i = 0; i < 4; ++i)
          acc[j][i] = __builtin_amdgcn_mfma_f32_16x16x32_bf16(bfr[j], af[i], acc[j][i], 0, 0, 0);
    }
  }

  #pragma unroll
  for (int j = 0; j < 4; ++j) {
    int nb = n0 + wc + j * 16 + rg * 4;
    f32x4 bo4 = *(const f32x4*)(bo + nb);
    #pragma unroll
    for (int i = 0; i < 4; ++i) {
      int m = m0 + wr + i * 16 + cl;
      f32x4 x4 = *(const f32x4*)(x + (size_t)m * 512 + nb);
      f32x4 o;
      #pragma unroll
      for (int r = 0; r < 4; ++r) o[r] = acc[j][i][r] + bo4[r] + x4[r];
      *(f32x4*)(out + (size_t)m * 512 + nb) = o;
    }
  }
}

extern "C" void kernel_launch(void* const* d_in, const int* in_sizes, int n_in,
                              void* d_out, int out_size, void* d_ws, size_t ws_size,
                              hipStream_t stream) {
  const float* x     = (const float*)d_in[0];
  const float* wq    = (const float*)d_in[1];
  const float* bq    = (const float*)d_in[2];
  const float* wk    = (const float*)d_in[3];
  const float* bk    = (const float*)d_in[4];
  const float* wv    = (const float*)d_in[5];
  const float* bv    = (const float*)d_in[6];
  const float* wo    = (const float*)d_in[7];
  const float* bo    = (const float*)d_in[8];
  const float* gamma = (const float*)d_in[9];
  const float* beta  = (const float*)d_in[10];

  char* ws = (char*)d_ws;
  unsigned short* xn   = (unsigned short*)(ws);              //  8,388,608 B
  unsigned short* wqkv = (unsigned short*)(ws + 8388608);    //  1,572,864 B
  float*          rinv = (float*)(ws + 8388608);             //  overlaps wqkv (dead by then)
  unsigned short* wob  = (unsigned short*)(ws + 9961472);    //    524,288 B
  unsigned short* qb   = (unsigned short*)(ws + 10485760);   //  8,388,608 B
  unsigned short* kb   = (unsigned short*)(ws + 18874368);   //  8,388,608 B
  unsigned short* vT   = (unsigned short*)(ws + 27262976);   //  8,388,608 B
  unsigned short* ctx  = (unsigned short*)(ws + 35651584);   //  8,388,608 B

  float* out  = (float*)d_out;
  float* attn = (float*)d_out + 4194304;

  ln_kernel<<<8192, 256, 0, stream>>>(x, gamma, beta, xn);
  cast_w_kernel<<<1024, 256, 0, stream>>>(wq, wk, wv, wo, wqkv, wob);
  qkv_gemm<<<dim3(64, 12), 256, 0, stream>>>(xn, wqkv, bq, bk, bv, qb, kb, vT);
  psum_kernel<<<1024, 256, 0, stream>>>(qb, kb, rinv);
  attn_kernel<<<1024, 256, 0, stream>>>(qb, kb, vT, rinv, attn, ctx);
  out_gemm<<<dim3(64, 4), 256, 0, stream>>>(ctx, wob, bo, x, out);
}

// Round 5
// 214.135 us; speedup vs baseline: 1.7185x; 1.0076x over previous
//
#include <hip/hip_runtime.h>

#define B_   4
#define H_   8
#define M_   2048
#define D_   512
#define DH_  64

typedef short  bf16x8 __attribute__((ext_vector_type(8)));
typedef float  f32x4  __attribute__((ext_vector_type(4)));
typedef unsigned short u16x4 __attribute__((ext_vector_type(4)));

#define EXPC 0.18033688011112042f   /* log2(e)/8 : exp(s/8) == exp2(s*EXPC) */

static __device__ __forceinline__ unsigned short f2bf(float f) {
  unsigned u = __float_as_uint(f);
  u += 0x7fffu + ((u >> 16) & 1u);
  return (unsigned short)(u >> 16);
}

static __device__ __forceinline__ int swz128(int row, int byteoff) {
  return row * 128 + (byteoff ^ ((row & 7) << 4));
}

// async global->LDS, 16B per lane, LDS dest = wave-uniform base + lane*16
static __device__ __forceinline__ void glds16(const void* g, void* l) {
  __builtin_amdgcn_global_load_lds(
      (const __attribute__((address_space(1))) unsigned*)g,
      (__attribute__((address_space(3))) unsigned*)l, 16, 0, 0);
}

// stage a 128-row x 128-byte tile (16KB) into LDS in swz128 layout:
// linear LDS dest (glds requirement), inverse-swizzled global source.
static __device__ __forceinline__ void stage_tile(
    const char* g0, size_t rstride, char* lds, int t) {
  const int r0 = t >> 3, c0 = t & 7;
  const char* src = g0 + (size_t)r0 * rstride + ((c0 ^ (r0 & 7)) << 4);
  char* dst = lds + ((t & 192) << 4);
  #pragma unroll
  for (int c = 0; c < 4; ++c)
    glds16(src + (size_t)c * 32 * rstride, dst + c * 4096);
}

// ---------------- LayerNorm -> bf16 ----------------
__global__ __launch_bounds__(256) void ln_kernel(
    const float* __restrict__ x, const float* __restrict__ gamma,
    const float* __restrict__ beta, unsigned short* __restrict__ xn)
{
  int row = blockIdx.x;
  int t = threadIdx.x;
  const float* xr = x + (size_t)row * D_;
  float v0 = xr[t], v1 = xr[t + 256];
  float s = v0 + v1, ss = v0 * v0 + v1 * v1;
  #pragma unroll
  for (int m = 1; m < 64; m <<= 1) {
    s  += __shfl_xor(s, m);
    ss += __shfl_xor(ss, m);
  }
  __shared__ float red[8];
  int wid = t >> 6;
  if ((t & 63) == 0) { red[wid] = s; red[wid + 4] = ss; }
  __syncthreads();
  s  = red[0] + red[1] + red[2] + red[3];
  ss = red[4] + red[5] + red[6] + red[7];
  float mu  = s * (1.0f / D_);
  float var = ss * (1.0f / D_) - mu * mu;
  float rstd = rsqrtf(var + 1e-5f);
  unsigned short* o = xn + (size_t)row * D_;
  o[t]       = f2bf((v0 - mu) * rstd * gamma[t]       + beta[t]);
  o[t + 256] = f2bf((v1 - mu) * rstd * gamma[t + 256] + beta[t + 256]);
}

// ---------------- weight casts ----------------
__global__ __launch_bounds__(256) void cast_w_kernel(
    const float* __restrict__ wq, const float* __restrict__ wk,
    const float* __restrict__ wv, const float* __restrict__ wo,
    unsigned short* __restrict__ wqkv, unsigned short* __restrict__ wob)
{
  int i = blockIdx.x * 256 + threadIdx.x;   // 262144 total
  wqkv[i]          = f2bf(wq[i]);
  wqkv[i + 262144] = f2bf(wk[i]);
  wqkv[i + 524288] = f2bf(wv[i]);
  wob[i]           = f2bf(wo[i]);
}

// ---------------- QKV GEMM: [8192,512] x [1536,512]^T (glds staging) -------
__global__ __launch_bounds__(256) void qkv_gemm(
    const unsigned short* __restrict__ xn,
    const unsigned short* __restrict__ wqkv,
    const float* __restrict__ bq, const float* __restrict__ bk,
    const float* __restrict__ bv,
    unsigned short* __restrict__ q, unsigned short* __restrict__ k,
    unsigned short* __restrict__ vT)
{
  __shared__ __align__(16) char As[128 * 128];
  __shared__ __align__(16) char Bs[128 * 128];
  const int m0 = blockIdx.x * 128;
  const int n0 = blockIdx.y * 128;
  const int t = threadIdx.x, wid = t >> 6, lane = t & 63;
  const int wr = (wid >> 1) * 64, wc = (wid & 1) * 64;
  const int cl = lane & 15, rg = lane >> 4;
  const f32x4 z4 = {0.f, 0.f, 0.f, 0.f};
  const bool isv = (n0 >= 1024);

  const char* agb = (const char*)xn   + (size_t)m0 * 1024;
  const char* bgb = (const char*)wqkv + (size_t)n0 * 1024;

  f32x4 acc[4][4];
  #pragma unroll
  for (int i = 0; i < 4; ++i)
    #pragma unroll
    for (int j = 0; j < 4; ++j) acc[i][j] = z4;

  for (int k0 = 0; k0 < 512; k0 += 64) {
    __syncthreads();
    stage_tile(agb + k0 * 2, 1024, As, t);
    stage_tile(bgb + k0 * 2, 1024, Bs, t);
    __syncthreads();
    #pragma unroll
    for (int ks = 0; ks < 2; ++ks) {
      int koff = ks * 64 + rg * 16;
      bf16x8 af[4], bfr[4];
      #pragma unroll
      for (int i = 0; i < 4; ++i)
        af[i] = *(const bf16x8*)(As + swz128(wr + i * 16 + cl, koff));
      #pragma unroll
      for (int j = 0; j < 4; ++j)
        bfr[j] = *(const bf16x8*)(Bs + swz128(wc + j * 16 + cl, koff));
      if (isv) {
        #pragma unroll
        for (int i = 0; i < 4; ++i)
          #pragma unroll
          for (int j = 0; j < 4; ++j)
            acc[i][j] = __builtin_amdgcn_mfma_f32_16x16x32_bf16(af[i], bfr[j], acc[i][j], 0, 0, 0);
      } else {
        #pragma unroll
        for (int j = 0; j < 4; ++j)
          #pragma unroll
          for (int i = 0; i < 4; ++i)
            acc[j][i] = __builtin_amdgcn_mfma_f32_16x16x32_bf16(bfr[j], af[i], acc[j][i], 0, 0, 0);
      }
    }
  }

  if (isv) {
    #pragma unroll
    for (int j = 0; j < 4; ++j) {
      int n = n0 + wc + j * 16 + cl;
      int nn = n & 511;
      int h = nn >> 6, dh = nn & 63;
      float bias = bv[nn];
      #pragma unroll
      for (int i = 0; i < 4; ++i) {
        int mrow = m0 + wr + i * 16 + rg * 4;
        int b = mrow >> 11, mm = mrow & 2047;
        u16x4 u;
        #pragma unroll
        for (int r = 0; r < 4; ++r) u[r] = f2bf(acc[i][j][r] + bias);
        *(u16x4*)(vT + ((size_t)(b * H_ + h) * DH_ + dh) * M_ + mm) = u;
      }
    }
  } else {
    const int mat = n0 >> 9;                  // 0: q, 1: k
    unsigned short* dst = mat ? k : q;
    const float* bias = mat ? bk : bq;
    #pragma unroll
    for (int j = 0; j < 4; ++j) {
      int nn0 = ((n0 + wc) & 511) + j * 16 + rg * 4;
      int h = nn0 >> 6, dh = nn0 & 63;
      f32x4 b4 = *(const f32x4*)(bias + nn0);
      #pragma unroll
      for (int i = 0; i < 4; ++i) {
        int mrow = m0 + wr + i * 16 + cl;
        int b = mrow >> 11, mm = mrow & 2047;
        u16x4 u;
        #pragma unroll
        for (int r = 0; r < 4; ++r) u[r] = f2bf(acc[j][i][r] + b4[r]);
        *(u16x4*)(dst + ((size_t)(b * H_ + h) * M_ + mm) * DH_ + dh) = u;
      }
    }
  }
}

// ---------------- psum: rinv[bh][m] = 1/sum_n exp(s/8), diag excluded -------
__global__ __launch_bounds__(256, 8) void psum_kernel(
    const unsigned short* __restrict__ q, const unsigned short* __restrict__ k,
    float* __restrict__ rinv)
{
  __shared__ __align__(16) char Kb[2][8192];
  const int flat = blockIdx.x;
  const int bh = (flat & 7) * 4 + ((flat >> 3) >> 5);
  const int mb = (flat >> 3) & 31;
  const int m0 = mb * 64;
  const int t = threadIdx.x, wid = t >> 6, lane = t & 63;
  const int wr = wid * 16, cl = lane & 15, rg = lane >> 4;
  const char* qb = (const char*)(q + (size_t)bh * M_ * DH_);
  const char* kb = (const char*)(k + (size_t)bh * M_ * DH_);
  const int m_g = m0 + wr + cl;
  const f32x4 z4 = {0.f, 0.f, 0.f, 0.f};

  bf16x8 qf[2];
  #pragma unroll
  for (int ks = 0; ks < 2; ++ks)
    qf[ks] = *(const bf16x8*)(qb + (size_t)m_g * 128 + ks * 64 + rg * 16);

  const int r0 = t >> 3, c0 = t & 7;
  const int ldsoff = (t & 192) * 16;                       // wave-uniform
  const size_t sK0 = (size_t)r0 * 128 + ((c0 ^ (r0 & 7)) << 4);

  glds16(kb + sK0,        Kb[0] + ldsoff);
  glds16(kb + sK0 + 4096, Kb[0] + ldsoff + 4096);

  float psum = 0.f;
  int buf = 0;
  for (int nt = 0; nt < 32; ++nt) {
    __syncthreads();
    if (nt + 1 < 32) {
      const char* src = kb + (size_t)(nt + 1) * 8192;
      glds16(src + sK0,        Kb[buf ^ 1] + ldsoff);
      glds16(src + sK0 + 4096, Kb[buf ^ 1] + ldsoff + 4096);
    }
    f32x4 s[4];
    #pragma unroll
    for (int j = 0; j < 4; ++j) s[j] = z4;
    #pragma unroll
    for (int ks = 0; ks < 2; ++ks)
      #pragma unroll
      for (int j = 0; j < 4; ++j) {
        bf16x8 kf = *(const bf16x8*)(Kb[buf] + swz128(j * 16 + cl, ks * 64 + rg * 16));
        s[j] = __builtin_amdgcn_mfma_f32_16x16x32_bf16(kf, qf[ks], s[j], 0, 0, 0);
      }
    if (nt == mb) {
      #pragma unroll
      for (int j = 0; j < 4; ++j)
        #pragma unroll
        for (int r = 0; r < 4; ++r) {
          int n_g = nt * 64 + j * 16 + rg * 4 + r;
          float p = __builtin_amdgcn_exp2f(s[j][r] * EXPC);
          psum += (n_g == m_g) ? 0.f : p;
        }
    } else {
      #pragma unroll
      for (int j = 0; j < 4; ++j)
        #pragma unroll
        for (int r = 0; r < 4; ++r)
          psum += __builtin_amdgcn_exp2f(s[j][r] * EXPC);
    }
    buf ^= 1;
  }
  psum += __shfl_xor(psum, 16);
  psum += __shfl_xor(psum, 32);
  if (lane < 16) rinv[bh * M_ + m_g] = 1.0f / psum;
}

// ---------------- Attention v5: counted-vmcnt barrier (stores stay in flight)
// grid 1024 (XCD-swizzled); 64 rows/block, 4 waves x 16 rows.
__global__ __launch_bounds__(256, 4) void attn_kernel(
    const unsigned short* __restrict__ q,
    const unsigned short* __restrict__ k,
    const unsigned short* __restrict__ vT,
    const float* __restrict__ rinv,
    float* __restrict__ attn,
    unsigned short* __restrict__ ctx)
{
  __shared__ __align__(16) char Kb[2][8192];
  __shared__ __align__(16) char Vb[2][8192];
  __shared__ __align__(16) char Ps[4][2048];

  const int flat = blockIdx.x;
  const int bh = (flat & 7) * 4 + ((flat >> 3) >> 5);
  const int mb = (flat >> 3) & 31;
  const int m0 = mb * 64;
  const int t = threadIdx.x, wid = t >> 6, lane = t & 63;
  const int wr = wid * 16, cl = lane & 15, rg = lane >> 4;
  const int m_g = m0 + wr + cl;
  const f32x4 z4 = {0.f, 0.f, 0.f, 0.f};

  const char* qb = (const char*)(q  + (size_t)bh * M_ * DH_);
  const char* kb = (const char*)(k  + (size_t)bh * M_ * DH_);
  const char* vb = (const char*)(vT + (size_t)bh * DH_ * M_);
  float* ab = attn + (size_t)bh * M_ * M_;

  const float rv = rinv[bh * M_ + m_g];
  bf16x8 qf[2];
  #pragma unroll
  for (int ks = 0; ks < 2; ++ks)
    qf[ks] = *(const bf16x8*)(qb + (size_t)m_g * 128 + ks * 64 + rg * 16);

  const int r0 = t >> 3, c0 = t & 7;
  const int ldsoff = (t & 192) * 16;                       // wave-uniform
  const size_t sK0 = (size_t)r0 * 128 + ((c0 ^ (r0 & 7)) << 4);
  const size_t sV0 = (size_t)r0 * (M_ * 2) + ((c0 ^ (r0 & 7)) << 4);

  glds16(kb + sK0,                    Kb[0] + ldsoff);
  glds16(kb + sK0 + 4096,             Kb[0] + ldsoff + 4096);
  glds16(vb + sV0,                    Vb[0] + ldsoff);
  glds16(vb + sV0 + 32 * (M_ * 2),    Vb[0] + ldsoff + 4096);
  __syncthreads();                    // vmcnt(0): tile 0 ready

  f32x4 oc[4];
  #pragma unroll
  for (int j = 0; j < 4; ++j) oc[j] = z4;

  const int srow = lane >> 4;          // attn-store row-in-group 0..3
  const int sch  = lane & 15;          // attn-store 8B-chunk 0..15

  int buf = 0;
  for (int nt = 0; nt < 32; ++nt) {
    // prefetch next tile early (4 VMEM, oldest in queue)
    if (nt + 1 < 32) {
      const char* srcK = kb + (size_t)(nt + 1) * 8192;
      const char* srcV = vb + (size_t)(nt + 1) * 128;
      glds16(srcK + sK0,                 Kb[buf ^ 1] + ldsoff);
      glds16(srcK + sK0 + 4096,          Kb[buf ^ 1] + ldsoff + 4096);
      glds16(srcV + sV0,                 Vb[buf ^ 1] + ldsoff);
      glds16(srcV + sV0 + 32 * (M_ * 2), Vb[buf ^ 1] + ldsoff + 4096);
    }
    // QK^T (swapped: rows = n, cols = m)
    f32x4 s[4];
    #pragma unroll
    for (int j = 0; j < 4; ++j) s[j] = z4;
    #pragma unroll
    for (int ks = 0; ks < 2; ++ks)
      #pragma unroll
      for (int j = 0; j < 4; ++j) {
        bf16x8 kf = *(const bf16x8*)(Kb[buf] + swz128(j * 16 + cl, ks * 64 + rg * 16));
        s[j] = __builtin_amdgcn_mfma_f32_16x16x32_bf16(kf, qf[ks], s[j], 0, 0, 0);
      }
    // normalized P -> per-wave LDS (bf16)
    const bool dtile = (nt == mb);
    #pragma unroll
    for (int j = 0; j < 4; ++j) {
      u16x4 u;
      #pragma unroll
      for (int r = 0; r < 4; ++r) {
        int n_g = nt * 64 + j * 16 + rg * 4 + r;
        float p = __builtin_amdgcn_exp2f(s[j][r] * EXPC) * rv;
        u[r] = f2bf((dtile && n_g == m_g) ? 0.f : p);
      }
      *(u16x4*)(Ps[wid] + swz128(cl, j * 32 + rg * 8)) = u;
    }
    // attn store: 4 NT f32x4 per lane (4 rows x 256B per instruction), youngest in queue
    {
      float* abase = ab + ((size_t)(m0 + wr + srow)) * M_ + nt * 64 + sch * 4;
      #pragma unroll
      for (int it = 0; it < 4; ++it) {
        u16x4 pu = *(const u16x4*)(Ps[wid] + swz128(it * 4 + srow, sch * 8));
        f32x4 pv;
        #pragma unroll
        for (int r = 0; r < 4; ++r) pv[r] = __uint_as_float((unsigned)pu[r] << 16);
        __builtin_nontemporal_store(pv, (f32x4*)(abase + (size_t)it * 4 * M_));
      }
    }
    // PV (swapped: rows = d, cols = m)
    #pragma unroll
    for (int ks = 0; ks < 2; ++ks) {
      bf16x8 pf = *(const bf16x8*)(Ps[wid] + swz128(cl, ks * 64 + rg * 16));
      #pragma unroll
      for (int jd = 0; jd < 4; ++jd) {
        bf16x8 vf = *(const bf16x8*)(Vb[buf] + swz128(jd * 16 + cl, ks * 64 + rg * 16));
        oc[jd] = __builtin_amdgcn_mfma_f32_16x16x32_bf16(vf, pf, oc[jd], 0, 0, 0);
      }
    }
    // counted barrier: drain the 4 prefetch glds (oldest), leave NT stores in flight
    if (nt + 1 < 32) {
      asm volatile("s_waitcnt vmcnt(4) lgkmcnt(0)" ::: "memory");
      __builtin_amdgcn_s_barrier();
    }
    buf ^= 1;
  }

  // ctx epilogue: lane holds 4 consecutive d for its row m_g
  int b = bh >> 3, h = bh & 7;
  unsigned short* crow = ctx + ((size_t)b * M_ + m_g) * D_ + h * DH_ + rg * 4;
  #pragma unroll
  for (int jd = 0; jd < 4; ++jd) {
    u16x4 u;
    #pragma unroll
    for (int r = 0; r < 4; ++r) u[r] = f2bf(oc[jd][r]);
    *(u16x4*)(crow + jd * 16) = u;
  }
}

// ---------------- out = ctx @ wo^T + bo + x (glds staging) ------------------
__global__ __launch_bounds__(256) void out_gemm(
    const unsigned short* __restrict__ ctxb,
    const unsigned short* __restrict__ wob,
    const float* __restrict__ bo,
    const float* __restrict__ x,
    float* __restrict__ out)
{
  __shared__ __align__(16) char As[128 * 128];
  __shared__ __align__(16) char Bs[128 * 128];
  const int m0 = blockIdx.x * 128;
  const int n0 = blockIdx.y * 128;
  const int t = threadIdx.x, wid = t >> 6, lane = t & 63;
  const int wr = (wid >> 1) * 64, wc = (wid & 1) * 64;
  const int cl = lane & 15, rg = lane >> 4;
  const f32x4 z4 = {0.f, 0.f, 0.f, 0.f};

  const char* agb = (const char*)ctxb + (size_t)m0 * 1024;
  const char* bgb = (const char*)wob  + (size_t)n0 * 1024;

  f32x4 acc[4][4];   // [j: n frag][i: m frag], row=n, col=m
  #pragma unroll
  for (int j = 0; j < 4; ++j)
    #pragma unroll
    for (int i = 0; i < 4; ++i) acc[j][i] = z4;

  for (int k0 = 0; k0 < 512; k0 += 64) {
    __syncthreads();
    stage_tile(agb + k0 * 2, 1024, As, t);
    stage_tile(bgb + k0 * 2, 1024, Bs, t);
    __syncthreads();
    #pragma unroll
    for (int ks = 0; ks < 2; ++ks) {
      int koff = ks * 64 + rg * 16;
      bf16x8 af[4], bfr[4];
      #pragma unroll
      for (int i = 0; i < 4; ++i)
        af[i] = *(const bf16x8*)(As + swz128(wr + i * 16 + cl, koff));
      #pragma unroll
      for (int j = 0; j < 4; ++j)
        bfr[j] = *(const bf16x8*)(Bs + swz128(wc + j * 16 + cl, koff));
      #pragma unroll
      for (int j = 0; j < 4; ++j)
        #pragma unroll
        for (int i = 0; i < 4; ++i)
          acc[j][i] = __builtin_amdgcn_mfma_f32_16x16x32_bf16(bfr[j], af[i], acc[j][i], 0, 0, 0);
    }
  }

  #pragma unroll
  for (int j = 0; j < 4; ++j) {
    int nb = n0 + wc + j * 16 + rg * 4;
    f32x4 bo4 = *(const f32x4*)(bo + nb);
    #pragma unroll
    for (int i = 0; i < 4; ++i) {
      int m = m0 + wr + i * 16 + cl;
      f32x4 x4 = *(const f32x4*)(x + (size_t)m * 512 + nb);
      f32x4 o;
      #pragma unroll
      for (int r = 0; r < 4; ++r) o[r] = acc[j][i][r] + bo4[r] + x4[r];
      *(f32x4*)(out + (size_t)m * 512 + nb) = o;
    }
  }
}

extern "C" void kernel_launch(void* const* d_in, const int* in_sizes, int n_in,
                              void* d_out, int out_size, void* d_ws, size_t ws_size,
                              hipStream_t stream) {
  const float* x     = (const float*)d_in[0];
  const float* wq    = (const float*)d_in[1];
  const float* bq    = (const float*)d_in[2];
  const float* wk    = (const float*)d_in[3];
  const float* bk    = (const float*)d_in[4];
  const float* wv    = (const float*)d_in[5];
  const float* bv    = (const float*)d_in[6];
  const float* wo    = (const float*)d_in[7];
  const float* bo    = (const float*)d_in[8];
  const float* gamma = (const float*)d_in[9];
  const float* beta  = (const float*)d_in[10];

  char* ws = (char*)d_ws;
  unsigned short* xn   = (unsigned short*)(ws);              //  8,388,608 B
  unsigned short* wqkv = (unsigned short*)(ws + 8388608);    //  1,572,864 B
  float*          rinv = (float*)(ws + 8388608);             //  overlaps wqkv (dead by then)
  unsigned short* wob  = (unsigned short*)(ws + 9961472);    //    524,288 B
  unsigned short* qb   = (unsigned short*)(ws + 10485760);   //  8,388,608 B
  unsigned short* kb   = (unsigned short*)(ws + 18874368);   //  8,388,608 B
  unsigned short* vT   = (unsigned short*)(ws + 27262976);   //  8,388,608 B
  unsigned short* ctx  = (unsigned short*)(ws + 35651584);   //  8,388,608 B

  float* out  = (float*)d_out;
  float* attn = (float*)d_out + 4194304;

  ln_kernel<<<8192, 256, 0, stream>>>(x, gamma, beta, xn);
  cast_w_kernel<<<1024, 256, 0, stream>>>(wq, wk, wv, wo, wqkv, wob);
  qkv_gemm<<<dim3(64, 12), 256, 0, stream>>>(xn, wqkv, bq, bk, bv, qb, kb, vT);
  psum_kernel<<<1024, 256, 0, stream>>>(qb, kb, rinv);
  attn_kernel<<<1024, 256, 0, stream>>>(qb, kb, vT, rinv, attn, ctx);
  out_gemm<<<dim3(64, 4), 256, 0, stream>>>(ctx, wob, bo, x, out);
}